// Round 3
// baseline (1563.437 us; speedup 1.0000x reference)
//
#include <hip/hip_runtime.h>

#define DD 128

typedef unsigned short u16;
typedef unsigned int   u32;

__device__ __forceinline__ float blo(u32 u){ return __uint_as_float(u << 16); }
__device__ __forceinline__ u16 f2b(float f){
    u32 u = __float_as_uint(f);
    u32 r = u + 0x7FFFu + ((u >> 16) & 1u);
    return (u16)(r >> 16);
}

// ---------------- runtime environment detection ----------------
// flags[0] = 1 if h is int64 (read as int32 pairs, take low word)
// flags[1] = 1 if float inputs are f32 (else packed bf16)
__global__ __launch_bounds__(256) void detect_kernel(const int* __restrict__ h32, int E,
                                                     const u32* __restrict__ xw,
                                                     int* __restrict__ flags)
{
    __shared__ int nzodd, sane;
    if (threadIdx.x == 0) { nzodd = 0; sane = 0; }
    __syncthreads();
    // int64 test: odd int32 words of the first 64 h-entries are all zero iff int64
    if (threadIdx.x < 64 && h32[2 * threadIdx.x + 1] != 0) atomicAdd(&nzodd, 1);
    // dtype test: low u16 of each 32-bit word of x has a sane bf16 exponent iff packed bf16
    for (int i = (int)threadIdx.x; i < 1024; i += 256) {
        u32 lo = xw[i] & 0xFFFFu;
        u32 ex = (lo >> 7) & 0xFFu;
        if (ex >= 100u && ex <= 140u) atomicAdd(&sane, 1);
    }
    __syncthreads();
    if (threadIdx.x == 0) {
        flags[0] = (nzodd == 0) ? 1 : 0;
        flags[1] = (sane < 700) ? 1 : 0;
    }
}

// ---------------- weight/bias canonicalization to f32 ----------------
// canonW: [Ww1 | Wx1 | Wx2 | Ww2] 4x16384 ; canonB: [bw1 | bx1 | bx2 | bw2] 4x128
__global__ __launch_bounds__(256) void canon_kernel(
    const int* __restrict__ flags,
    const void* W0, const void* W1, const void* W2, const void* W3,
    const void* B0, const void* B1, const void* B2, const void* B3,
    float* __restrict__ canonW, float* __restrict__ canonB)
{
    int idx = blockIdx.x * 256 + threadIdx.x;
    bool f32 = (flags[1] != 0);
    const void* src; int o; float* dst; int doff;
    if (idx < 65536) {
        int m = idx >> 14; o = idx & 16383;
        switch (m) { case 0: src = W0; break; case 1: src = W1; break;
                     case 2: src = W2; break; default: src = W3; }
        dst = canonW; doff = idx;
    } else {
        int j = idx - 65536; if (j >= 512) return;
        int m = j >> 7; o = j & 127;
        switch (m) { case 0: src = B0; break; case 1: src = B1; break;
                     case 2: src = B2; break; default: src = B3; }
        dst = canonB; doff = j;
    }
    float v = f32 ? ((const float*)src)[o] : blo(((const u16*)src)[o]);
    dst[doff] = v;
}

// ---------------- CSR build ----------------
__device__ __forceinline__ void load_edge(const int* __restrict__ h32, int e, int E,
                                          int idx64, int& v, int& u)
{
    if (idx64) { v = h32[2 * e]; u = h32[2 * E + 2 * e]; }
    else       { v = h32[e];     u = h32[E + e]; }
}

__global__ __launch_bounds__(256) void hist_kernel(const int* __restrict__ flags,
                                                   const int* __restrict__ h32,
                                                   int* __restrict__ cnt, int E, int NX)
{
    int e = blockIdx.x * 256 + threadIdx.x;
    if (e >= E) return;
    int v, u; load_edge(h32, e, E, flags[0], v, u);
    atomicAdd(&cnt[v], 1);
    atomicAdd(&cnt[NX + u], 1);
}

__global__ __launch_bounds__(1024) void tile_sum_kernel(const int* __restrict__ cnt, int n,
                                                        int* __restrict__ part)
{
    __shared__ int s[1024];
    int t = threadIdx.x;
    int i = blockIdx.x * 1024 + t;
    s[t] = (i < n) ? cnt[i] : 0;
    __syncthreads();
    for (int st = 512; st > 0; st >>= 1) {
        if (t < st) s[t] += s[t + st];
        __syncthreads();
    }
    if (t == 0) part[blockIdx.x] = s[0];
}

__global__ __launch_bounds__(1024) void part_scan_kernel(int* __restrict__ part, int nb,
                                                         int* __restrict__ off, int ntot)
{
    __shared__ int s[1024];
    int t = threadIdx.x;
    int orig = (t < nb) ? part[t] : 0;
    s[t] = orig;
    __syncthreads();
    for (int st = 1; st < 1024; st <<= 1) {
        int add = (t >= st) ? s[t - st] : 0;
        __syncthreads();
        s[t] += add;
        __syncthreads();
    }
    if (t < nb) part[t] = s[t] - orig;     // exclusive tile offsets
    if (t == 1023) off[ntot] = s[1023];    // grand total = 2E
}

__global__ __launch_bounds__(1024) void tile_scan_kernel(const int* __restrict__ cnt, int n,
                                                         const int* __restrict__ part,
                                                         int* __restrict__ off,
                                                         int* __restrict__ cur)
{
    __shared__ int s[1024];
    int t = threadIdx.x;
    int i = blockIdx.x * 1024 + t;
    int orig = (i < n) ? cnt[i] : 0;
    s[t] = orig;
    __syncthreads();
    for (int st = 1; st < 1024; st <<= 1) {
        int add = (t >= st) ? s[t - st] : 0;
        __syncthreads();
        s[t] += add;
        __syncthreads();
    }
    if (i < n) {
        int excl = s[t] - orig + part[blockIdx.x];
        off[i] = excl;
        cur[i] = excl;
    }
}

__global__ __launch_bounds__(256) void fill_kernel(const int* __restrict__ flags,
                                                   const int* __restrict__ h32,
                                                   int* __restrict__ cur,
                                                   int* __restrict__ cv, int E, int NX)
{
    int e = blockIdx.x * 256 + threadIdx.x;
    if (e >= E) return;
    int v, u; load_edge(h32, e, E, flags[0], v, u);
    int pv = atomicAdd(&cur[v], 1);
    cv[pv] = u;                       // vertex rows: neighbor hyperedge ids, [0, E)
    int pe = atomicAdd(&cur[NX + u], 1);
    cv[pe] = v;                       // hyperedge rows: neighbor vertex ids, [E, 2E)
}

// ---------------- fused phase ----------------
// out[r] = (stab[r]@Ws^T + bs) * (1 + (sum_{nbr} gtab[nbr])@Wg^T + deg*bg)
// 256 threads: n = t&127 output feature, p = t>>7 owns k-half [64p, 64p+64).
template<bool F32>
__global__ __launch_bounds__(256) void fused_phase(
    const int* __restrict__ flags,
    const void* __restrict__ gtab_v, size_t goff,
    const void* __restrict__ stab_v,
    const float* __restrict__ Wg, const float* __restrict__ bg,
    const float* __restrict__ Ws, const float* __restrict__ bs,
    const int* __restrict__ off,
    const int* __restrict__ cv,
    void* __restrict__ out_v, size_t ooff, int M)
{
    if ((flags[1] != 0) != F32) return;   // wrong dtype variant: exit

    const int n = threadIdx.x & 127;
    const int p = threadIdx.x >> 7;

    const u16*   gt16 = (const u16*)gtab_v + goff;
    const float* gtf  = (const float*)gtab_v + goff;
    const u16*   st16 = (const u16*)stab_v;
    const float* stf  = (const float*)stab_v;
    u16*   o16 = (u16*)out_v + ooff;
    float* of  = (float*)out_v + ooff;

    // register-cache this thread's k-half of both weight rows (f32 canonical)
    float4 wg4[16], ws4[16];
    {
        const float4* gp = (const float4*)(Wg + n * DD + p * 64);
        const float4* sp = (const float4*)(Ws + n * DD + p * 64);
#pragma unroll
        for (int i = 0; i < 16; ++i) { wg4[i] = gp[i]; ws4[i] = sp[i]; }
    }
    const float bgn = bg[n];
    const float bsn = bs[n];

    __shared__ float sr[DD];   // gathered sum row
    __shared__ float xr[DD];   // self row
    __shared__ float pg[DD];   // p=1 partials
    __shared__ float ps[DD];

    const int VB = 16;
    int r0 = blockIdx.x * VB;
    for (int rr = 0; rr < VB; ++rr) {
        int r = r0 + rr;
        if (r >= M) return;    // uniform across block
        int start = off[r], end = off[r + 1];

        float acc = 0.f;
        for (int e = start + p; e < end; e += 2) {
            int idx = cv[e];
            acc += F32 ? gtf[(size_t)idx * DD + n] : blo(gt16[(size_t)idx * DD + n]);
        }
        if (p) pg[n] = acc;
        else   xr[n] = F32 ? stf[(size_t)r * DD + n] : blo(st16[(size_t)r * DD + n]);
        __syncthreads();
        if (!p) sr[n] = acc + pg[n];
        __syncthreads();

        float ag = 0.f, as_ = 0.f;
        const float* srk = sr + p * 64;
        const float* xrk = xr + p * 64;
#pragma unroll
        for (int i = 0; i < 16; ++i) {
            float4 g = wg4[i], s = ws4[i];
            ag  += srk[i*4+0]*g.x + srk[i*4+1]*g.y + srk[i*4+2]*g.z + srk[i*4+3]*g.w;
            as_ += xrk[i*4+0]*s.x + xrk[i*4+1]*s.y + xrk[i*4+2]*s.z + xrk[i*4+3]*s.w;
        }
        if (p) { pg[n] = ag; ps[n] = as_; }
        __syncthreads();
        if (!p) {
            float A = ag + pg[n] + (float)(end - start) * bgn;
            float S = as_ + ps[n] + bsn;
            float res = S * (1.f + A);
            if (F32) of[(size_t)r * DD + n] = res;
            else     o16[(size_t)r * DD + n] = f2b(res);
        }
        __syncthreads();
    }
}

static inline size_t alignup(size_t v){ return (v + 255) & ~(size_t)255; }

extern "C" void kernel_launch(void* const* d_in, const int* in_sizes, int n_in,
                              void* d_out, int out_size, void* d_ws, size_t ws_size,
                              hipStream_t stream)
{
    const int NX = in_sizes[0] / DD;    // 100000
    const int NW = in_sizes[1] / DD;    // 25000
    const int E  = in_sizes[10] / 2;    // 800000 (element count, width-independent)
    const int NT = NX + NW;

    const void* x   = d_in[0];
    const void* w   = d_in[1];
    const int*  h32 = (const int*)d_in[10];

    // workspace (~7.7 MB)
    char* ws = (char*)d_ws;
    size_t o = 0;
    int*   flags   = (int*)(ws + o); o = alignup(o + sizeof(int) * 8);
    int*   off_all = (int*)(ws + o); o = alignup(o + sizeof(int) * (size_t)(NT + 1));
    int*   cur_all = (int*)(ws + o); o = alignup(o + sizeof(int) * (size_t)NT);
    int*   part    = (int*)(ws + o); o = alignup(o + sizeof(int) * 1024);
    float* canonW  = (float*)(ws + o); o = alignup(o + sizeof(float) * 65536);
    float* canonB  = (float*)(ws + o); o = alignup(o + sizeof(float) * 512);
    int*   cv_all  = (int*)(ws + o); o = alignup(o + sizeof(int) * (size_t)2 * E);

    detect_kernel<<<1, 256, 0, stream>>>(h32, E, (const u32*)x, flags);

    canon_kernel<<<(66048 + 255) / 256, 256, 0, stream>>>(
        flags, d_in[4], d_in[2], d_in[6], d_in[8],   // Ww1, Wx1, Wx2, Ww2
               d_in[5], d_in[3], d_in[7], d_in[9],   // bw1, bx1, bx2, bw2
        canonW, canonB);

    hipMemsetAsync(cur_all, 0, sizeof(int) * (size_t)NT, stream);

    int eb = (E + 255) / 256;
    int nb = (NT + 1023) / 1024;
    hist_kernel<<<eb, 256, 0, stream>>>(flags, h32, cur_all, E, NX);
    tile_sum_kernel<<<nb, 1024, 0, stream>>>(cur_all, NT, part);
    part_scan_kernel<<<1, 1024, 0, stream>>>(part, nb, off_all, NT);
    tile_scan_kernel<<<nb, 1024, 0, stream>>>(cur_all, NT, part, off_all, cur_all);
    fill_kernel<<<eb, 256, 0, stream>>>(flags, h32, cur_all, cv_all, E, NX);

    // out layout: [w_new (NW*DD) | x_new (NX*DD)] in the detected output dtype
    size_t xoff = (size_t)NW * DD;

    // Phase 1 (MPToVertex): x_new = (x@Wx1^T+bx1) * (1 + segsum_v(w)@Ww1^T + deg_v*bw1)
    int g1 = (NX + 15) / 16;
    fused_phase<false><<<g1, 256, 0, stream>>>(flags, w, 0, x,
        canonW + 0 * 16384, canonB + 0, canonW + 1 * 16384, canonB + 128,
        off_all, cv_all, d_out, xoff, NX);
    fused_phase<true><<<g1, 256, 0, stream>>>(flags, w, 0, x,
        canonW + 0 * 16384, canonB + 0, canonW + 1 * 16384, canonB + 128,
        off_all, cv_all, d_out, xoff, NX);

    // Phase 2 (MPToEdge): w_new = (w@Ww2^T+bw2) * (1 + segsum_e(x_new)@Wx2^T + deg_e*bx2)
    int g2 = (NW + 15) / 16;
    fused_phase<false><<<g2, 256, 0, stream>>>(flags, d_out, xoff, w,
        canonW + 2 * 16384, canonB + 256, canonW + 3 * 16384, canonB + 384,
        off_all + NX, cv_all, d_out, 0, NW);
    fused_phase<true><<<g2, 256, 0, stream>>>(flags, d_out, xoff, w,
        canonW + 2 * 16384, canonB + 256, canonW + 3 * 16384, canonB + 384,
        off_all + NX, cv_all, d_out, 0, NW);
}

// Round 4
// 578.443 us; speedup vs baseline: 2.7028x; 2.7028x over previous
//
#include <hip/hip_runtime.h>

#define DD 128

typedef unsigned short u16;
typedef unsigned int   u32;
typedef __attribute__((ext_vector_type(8))) short bf16x8;
typedef __attribute__((ext_vector_type(4))) float f32x4;

__device__ __forceinline__ float blo(u32 u){ return __uint_as_float(u << 16); }
__device__ __forceinline__ float bhi(u32 u){ return __uint_as_float(u & 0xFFFF0000u); }
__device__ __forceinline__ u16 f2b(float f){
    u32 u = __float_as_uint(f);
    u32 r = u + 0x7FFFu + ((u >> 16) & 1u);
    return (u16)(r >> 16);
}

// ---------------- runtime environment detection ----------------
// flags[0] = 1 if h is int64 ; flags[1] = 1 if float inputs are f32
__global__ __launch_bounds__(256) void detect_kernel(const int* __restrict__ h32, int E,
                                                     const u32* __restrict__ xw,
                                                     int* __restrict__ flags)
{
    __shared__ int nzodd, sane;
    if (threadIdx.x == 0) { nzodd = 0; sane = 0; }
    __syncthreads();
    if (threadIdx.x < 64 && h32[2 * threadIdx.x + 1] != 0) atomicAdd(&nzodd, 1);
    for (int i = (int)threadIdx.x; i < 1024; i += 256) {
        u32 lo = xw[i] & 0xFFFFu;
        u32 ex = (lo >> 7) & 0xFFu;
        if (ex >= 100u && ex <= 140u) atomicAdd(&sane, 1);
    }
    __syncthreads();
    if (threadIdx.x == 0) {
        flags[0] = (nzodd == 0) ? 1 : 0;
        flags[1] = (sane < 700) ? 1 : 0;
    }
}

// ---------------- canonicalize weights (bf16) + biases (f32) ----------------
// Wb: [Ww1 | Wx1 | Wx2 | Ww2] 4x16384 bf16 ; canonB: [bw1 | bx1 | bx2 | bw2] f32
__global__ __launch_bounds__(256) void canon_kernel(
    const int* __restrict__ flags,
    const void* W0, const void* W1, const void* W2, const void* W3,
    const void* B0, const void* B1, const void* B2, const void* B3,
    u16* __restrict__ Wb, float* __restrict__ canonB)
{
    int idx = blockIdx.x * 256 + threadIdx.x;
    bool f32 = (flags[1] != 0);
    if (idx < 65536) {
        int m = idx >> 14, o = idx & 16383;
        const void* src;
        switch (m) { case 0: src = W0; break; case 1: src = W1; break;
                     case 2: src = W2; break; default: src = W3; }
        float v = f32 ? ((const float*)src)[o] : blo(((const u16*)src)[o]);
        Wb[idx] = f2b(v);
    } else {
        int j = idx - 65536; if (j >= 512) return;
        int m = j >> 7, o = j & 127;
        const void* src;
        switch (m) { case 0: src = B0; break; case 1: src = B1; break;
                     case 2: src = B2; break; default: src = B3; }
        canonB[j] = f32 ? ((const float*)src)[o] : blo(((const u16*)src)[o]);
    }
}

// ---------------- CSR build ----------------
__device__ __forceinline__ void load_edge(const int* __restrict__ h32, int e, int E,
                                          int idx64, int& v, int& u)
{
    if (idx64) { v = h32[2 * e]; u = h32[2 * E + 2 * e]; }
    else       { v = h32[e];     u = h32[E + e]; }
}

__global__ __launch_bounds__(256) void hist_kernel(const int* __restrict__ flags,
                                                   const int* __restrict__ h32,
                                                   int* __restrict__ cnt, int E, int NX)
{
    int e = blockIdx.x * 256 + threadIdx.x;
    if (e >= E) return;
    int v, u; load_edge(h32, e, E, flags[0], v, u);
    atomicAdd(&cnt[v], 1);
    atomicAdd(&cnt[NX + u], 1);
}

__global__ __launch_bounds__(1024) void tile_sum_kernel(const int* __restrict__ cnt, int n,
                                                        int* __restrict__ part)
{
    __shared__ int s[1024];
    int t = threadIdx.x;
    int i = blockIdx.x * 1024 + t;
    s[t] = (i < n) ? cnt[i] : 0;
    __syncthreads();
    for (int st = 512; st > 0; st >>= 1) {
        if (t < st) s[t] += s[t + st];
        __syncthreads();
    }
    if (t == 0) part[blockIdx.x] = s[0];
}

__global__ __launch_bounds__(1024) void part_scan_kernel(int* __restrict__ part, int nb,
                                                         int* __restrict__ off, int ntot)
{
    __shared__ int s[1024];
    int t = threadIdx.x;
    int orig = (t < nb) ? part[t] : 0;
    s[t] = orig;
    __syncthreads();
    for (int st = 1; st < 1024; st <<= 1) {
        int add = (t >= st) ? s[t - st] : 0;
        __syncthreads();
        s[t] += add;
        __syncthreads();
    }
    if (t < nb) part[t] = s[t] - orig;
    if (t == 1023) off[ntot] = s[1023];
}

__global__ __launch_bounds__(1024) void tile_scan_kernel(const int* __restrict__ cnt, int n,
                                                         const int* __restrict__ part,
                                                         int* __restrict__ off,
                                                         int* __restrict__ cur)
{
    __shared__ int s[1024];
    int t = threadIdx.x;
    int i = blockIdx.x * 1024 + t;
    int orig = (i < n) ? cnt[i] : 0;
    s[t] = orig;
    __syncthreads();
    for (int st = 1; st < 1024; st <<= 1) {
        int add = (t >= st) ? s[t - st] : 0;
        __syncthreads();
        s[t] += add;
        __syncthreads();
    }
    if (i < n) {
        int excl = s[t] - orig + part[blockIdx.x];
        off[i] = excl;
        cur[i] = excl;
    }
}

__global__ __launch_bounds__(256) void fill_kernel(const int* __restrict__ flags,
                                                   const int* __restrict__ h32,
                                                   int* __restrict__ cur,
                                                   int* __restrict__ cv, int E, int NX)
{
    int e = blockIdx.x * 256 + threadIdx.x;
    if (e >= E) return;
    int v, u; load_edge(h32, e, E, flags[0], v, u);
    int pv = atomicAdd(&cur[v], 1);
    cv[pv] = u;
    int pe = atomicAdd(&cur[NX + u], 1);
    cv[pe] = v;
}

// ---------------- fused phase: gather + double MFMA gemm + epilogue ----------------
// out[r] = (stab[r]@Ws^T + bs) * (1 + (sum_nbr gtab[nbr])@Wg^T + deg*bg)
// Block 256 = 4 waves, 16 rows. Wave gathers rows wv,wv+4,wv+8,wv+12 into LDS bf16.
// Then each wave computes cols [32*wv, 32*wv+32) of both matmuls via mfma 16x16x32.
__global__ __launch_bounds__(256) void fused_mfma_phase(
    const int* __restrict__ flags,
    const void* __restrict__ gtab, size_t goff,
    const void* __restrict__ stab,
    const u16* __restrict__ Wg, const u16* __restrict__ Ws,
    const float* __restrict__ bg, const float* __restrict__ bs,
    const int* __restrict__ off, const int* __restrict__ cv,
    void* __restrict__ out, size_t ooff, int M)
{
    const bool F32 = (flags[1] != 0);
    const int lane = threadIdx.x & 63;
    const int wid  = threadIdx.x >> 6;
    const int r0   = blockIdx.x * 16;

    __shared__ u16  sA[16][136];   // gathered-sum rows, bf16, padded (+8) for banks
    __shared__ u16  sS[16][136];   // self rows
    __shared__ float sdeg[16];

    // ---- gather stage (no barriers inside) ----
    for (int rr = wid; rr < 16; rr += 4) {
        int r = r0 + rr;
        float a0 = 0.f, a1 = 0.f, s0 = 0.f, s1 = 0.f;
        int deg = 0;
        if (r < M) {
            int start = off[r], end = off[r + 1];
            deg = end - start;
            int e = start;
            if (F32) {
                const float* gt = (const float*)gtab + goff;
                for (; e + 3 < end; e += 4) {
                    int i0 = cv[e], i1 = cv[e+1], i2 = cv[e+2], i3 = cv[e+3];
                    float2 v0 = *(const float2*)(gt + (size_t)i0 * DD + 2 * lane);
                    float2 v1 = *(const float2*)(gt + (size_t)i1 * DD + 2 * lane);
                    float2 v2 = *(const float2*)(gt + (size_t)i2 * DD + 2 * lane);
                    float2 v3 = *(const float2*)(gt + (size_t)i3 * DD + 2 * lane);
                    a0 += (v0.x + v1.x) + (v2.x + v3.x);
                    a1 += (v0.y + v1.y) + (v2.y + v3.y);
                }
                for (; e < end; ++e) {
                    float2 v = *(const float2*)(gt + (size_t)cv[e] * DD + 2 * lane);
                    a0 += v.x; a1 += v.y;
                }
                float2 sv = *(const float2*)((const float*)stab + (size_t)r * DD + 2 * lane);
                s0 = sv.x; s1 = sv.y;
            } else {
                const u16* gt = (const u16*)gtab + goff;
                for (; e + 3 < end; e += 4) {
                    int i0 = cv[e], i1 = cv[e+1], i2 = cv[e+2], i3 = cv[e+3];
                    u32 p0 = *(const u32*)(gt + (size_t)i0 * DD + 2 * lane);
                    u32 p1 = *(const u32*)(gt + (size_t)i1 * DD + 2 * lane);
                    u32 p2 = *(const u32*)(gt + (size_t)i2 * DD + 2 * lane);
                    u32 p3 = *(const u32*)(gt + (size_t)i3 * DD + 2 * lane);
                    a0 += (blo(p0) + blo(p1)) + (blo(p2) + blo(p3));
                    a1 += (bhi(p0) + bhi(p1)) + (bhi(p2) + bhi(p3));
                }
                for (; e < end; ++e) {
                    u32 p = *(const u32*)(gt + (size_t)cv[e] * DD + 2 * lane);
                    a0 += blo(p); a1 += bhi(p);
                }
                u32 sp = *(const u32*)((const u16*)stab + (size_t)r * DD + 2 * lane);
                s0 = blo(sp); s1 = bhi(sp);
            }
        }
        *(u32*)&sA[rr][2 * lane] = ((u32)f2b(a1) << 16) | (u32)f2b(a0);
        *(u32*)&sS[rr][2 * lane] = ((u32)f2b(s1) << 16) | (u32)f2b(s0);
        if (lane == 0) sdeg[rr] = (float)deg;
    }
    __syncthreads();

    // ---- MFMA stage: wave wid covers cols [32*wid, 32*wid+32) ----
    const int qk = (lane >> 4) * 8;     // this lane's k-offset within a frag
    const int fn = lane & 15;

    bf16x8 Bg[2][4], Bs[2][4];
#pragma unroll
    for (int t = 0; t < 2; ++t) {
        int n = 32 * wid + 16 * t + fn;
#pragma unroll
        for (int c = 0; c < 4; ++c) {
            Bg[t][c] = *(const bf16x8*)(Wg + (size_t)n * DD + 32 * c + qk);
            Bs[t][c] = *(const bf16x8*)(Ws + (size_t)n * DD + 32 * c + qk);
        }
    }

    f32x4 accA[2], accS[2];
#pragma unroll
    for (int t = 0; t < 2; ++t)
#pragma unroll
        for (int i = 0; i < 4; ++i) { accA[t][i] = 0.f; accS[t][i] = 0.f; }

#pragma unroll
    for (int c = 0; c < 4; ++c) {
        bf16x8 Ag = *(const bf16x8*)&sA[fn][32 * c + qk];
        bf16x8 As = *(const bf16x8*)&sS[fn][32 * c + qk];
#pragma unroll
        for (int t = 0; t < 2; ++t) {
            accA[t] = __builtin_amdgcn_mfma_f32_16x16x32_bf16(Ag, Bg[t][c], accA[t], 0, 0, 0);
            accS[t] = __builtin_amdgcn_mfma_f32_16x16x32_bf16(As, Bs[t][c], accS[t], 0, 0, 0);
        }
    }

    // ---- epilogue: D row=(lane>>4)*4+i, col=lane&15 (+tile base) ----
#pragma unroll
    for (int t = 0; t < 2; ++t) {
        int col = 32 * wid + 16 * t + fn;
        float bsv = bs[col], bgv = bg[col];
#pragma unroll
        for (int i = 0; i < 4; ++i) {
            int rr = (lane >> 4) * 4 + i;
            int r = r0 + rr;
            if (r >= M) continue;
            float S = accS[t][i] + bsv;
            float A = accA[t][i] + sdeg[rr] * bgv;
            float res = S * (1.f + A);
            if (F32) ((float*)out)[ooff + (size_t)r * DD + col] = res;
            else     ((u16*)out)[ooff + (size_t)r * DD + col] = f2b(res);
        }
    }
}

static inline size_t alignup(size_t v){ return (v + 255) & ~(size_t)255; }

extern "C" void kernel_launch(void* const* d_in, const int* in_sizes, int n_in,
                              void* d_out, int out_size, void* d_ws, size_t ws_size,
                              hipStream_t stream)
{
    const int NX = in_sizes[0] / DD;    // 100000
    const int NW = in_sizes[1] / DD;    // 25000
    const int E  = in_sizes[10] / 2;    // 800000
    const int NT = NX + NW;

    const void* x   = d_in[0];
    const void* w   = d_in[1];
    const int*  h32 = (const int*)d_in[10];

    // workspace (~7.7 MB)
    char* ws = (char*)d_ws;
    size_t o = 0;
    int*   flags   = (int*)(ws + o); o = alignup(o + sizeof(int) * 8);
    int*   off_all = (int*)(ws + o); o = alignup(o + sizeof(int) * (size_t)(NT + 1));
    int*   cur_all = (int*)(ws + o); o = alignup(o + sizeof(int) * (size_t)NT);
    int*   part    = (int*)(ws + o); o = alignup(o + sizeof(int) * 1024);
    u16*   Wb      = (u16*)(ws + o); o = alignup(o + sizeof(u16) * 65536);
    float* canonB  = (float*)(ws + o); o = alignup(o + sizeof(float) * 512);
    int*   cv_all  = (int*)(ws + o); o = alignup(o + sizeof(int) * (size_t)2 * E);

    detect_kernel<<<1, 256, 0, stream>>>(h32, E, (const u32*)x, flags);

    canon_kernel<<<(66048 + 255) / 256, 256, 0, stream>>>(
        flags, d_in[4], d_in[2], d_in[6], d_in[8],   // Ww1, Wx1, Wx2, Ww2
               d_in[5], d_in[3], d_in[7], d_in[9],   // bw1, bx1, bx2, bw2
        Wb, canonB);

    hipMemsetAsync(cur_all, 0, sizeof(int) * (size_t)NT, stream);

    int eb = (E + 255) / 256;
    int nb = (NT + 1023) / 1024;
    hist_kernel<<<eb, 256, 0, stream>>>(flags, h32, cur_all, E, NX);
    tile_sum_kernel<<<nb, 1024, 0, stream>>>(cur_all, NT, part);
    part_scan_kernel<<<1, 1024, 0, stream>>>(part, nb, off_all, NT);
    tile_scan_kernel<<<nb, 1024, 0, stream>>>(cur_all, NT, part, off_all, cur_all);
    fill_kernel<<<eb, 256, 0, stream>>>(flags, h32, cur_all, cv_all, E, NX);

    // out layout: [w_new (NW*DD) | x_new (NX*DD)] in detected dtype
    size_t xoff = (size_t)NW * DD;

    // Phase 1 (MPToVertex): x_new = (x@Wx1^T+bx1) * (1 + segsum_v(w)@Ww1^T + deg_v*bw1)
    fused_mfma_phase<<<(NX + 15) / 16, 256, 0, stream>>>(
        flags, w, 0, x,
        Wb + 0 * 16384, Wb + 1 * 16384, canonB + 0, canonB + 128,
        off_all, cv_all, d_out, xoff, NX);

    // Phase 2 (MPToEdge): w_new = (w@Ww2^T+bw2) * (1 + segsum_e(x_new)@Wx2^T + deg_e*bx2)
    fused_mfma_phase<<<(NW + 15) / 16, 256, 0, stream>>>(
        flags, d_out, xoff, w,
        Wb + 2 * 16384, Wb + 3 * 16384, canonB + 256, canonB + 384,
        off_all + NX, cv_all, d_out, 0, NW);
}

// Round 5
// 536.823 us; speedup vs baseline: 2.9124x; 1.0775x over previous
//
#include <hip/hip_runtime.h>

#define DD 128

typedef unsigned short u16;
typedef unsigned int   u32;
typedef __attribute__((ext_vector_type(8))) short bf16x8;
typedef __attribute__((ext_vector_type(4))) float f32x4;

__device__ __forceinline__ float blo(u32 u){ return __uint_as_float(u << 16); }
__device__ __forceinline__ float bhi(u32 u){ return __uint_as_float(u & 0xFFFF0000u); }
__device__ __forceinline__ u16 f2b(float f){
    u32 u = __float_as_uint(f);
    u32 r = u + 0x7FFFu + ((u >> 16) & 1u);
    return (u16)(r >> 16);
}

// ---------------- runtime environment detection ----------------
// flags[0] = 1 if h is int64 ; flags[1] = 1 if float inputs are f32
__global__ __launch_bounds__(256) void detect_kernel(const int* __restrict__ h32, int E,
                                                     const u32* __restrict__ xw,
                                                     int* __restrict__ flags)
{
    __shared__ int nzodd, sane;
    if (threadIdx.x == 0) { nzodd = 0; sane = 0; }
    __syncthreads();
    if (threadIdx.x < 64 && h32[2 * threadIdx.x + 1] != 0) atomicAdd(&nzodd, 1);
    for (int i = (int)threadIdx.x; i < 1024; i += 256) {
        u32 lo = xw[i] & 0xFFFFu;
        u32 ex = (lo >> 7) & 0xFFu;
        if (ex >= 100u && ex <= 140u) atomicAdd(&sane, 1);
    }
    __syncthreads();
    if (threadIdx.x == 0) {
        flags[0] = (nzodd == 0) ? 1 : 0;
        flags[1] = (sane < 700) ? 1 : 0;
    }
}

// ---------------- canonicalize weights (bf16) + biases (f32) ----------------
__global__ __launch_bounds__(256) void canon_kernel(
    const int* __restrict__ flags,
    const void* W0, const void* W1, const void* W2, const void* W3,
    const void* B0, const void* B1, const void* B2, const void* B3,
    u16* __restrict__ Wb, float* __restrict__ canonB)
{
    int idx = blockIdx.x * 256 + threadIdx.x;
    bool f32 = (flags[1] != 0);
    if (idx < 65536) {
        int m = idx >> 14, o = idx & 16383;
        const void* src;
        switch (m) { case 0: src = W0; break; case 1: src = W1; break;
                     case 2: src = W2; break; default: src = W3; }
        float v = f32 ? ((const float*)src)[o] : blo(((const u16*)src)[o]);
        Wb[idx] = f2b(v);
    } else {
        int j = idx - 65536; if (j >= 512) return;
        int m = j >> 7, o = j & 127;
        const void* src;
        switch (m) { case 0: src = B0; break; case 1: src = B1; break;
                     case 2: src = B2; break; default: src = B3; }
        canonB[j] = f32 ? ((const float*)src)[o] : blo(((const u16*)src)[o]);
    }
}

// ---------------- CSR build ----------------
__device__ __forceinline__ void load_edge(const int* __restrict__ h32, int e, int E,
                                          int idx64, int& v, int& u)
{
    if (idx64) { v = h32[2 * e]; u = h32[2 * E + 2 * e]; }
    else       { v = h32[e];     u = h32[E + e]; }
}

__global__ __launch_bounds__(256) void hist_kernel(const int* __restrict__ flags,
                                                   const int* __restrict__ h32,
                                                   int* __restrict__ cnt, int E, int NX)
{
    int e = blockIdx.x * 256 + threadIdx.x;
    if (e >= E) return;
    int v, u; load_edge(h32, e, E, flags[0], v, u);
    atomicAdd(&cnt[v], 1);
    atomicAdd(&cnt[NX + u], 1);
}

__global__ __launch_bounds__(1024) void tile_sum_kernel(const int* __restrict__ cnt, int n,
                                                        int* __restrict__ part)
{
    __shared__ int s[1024];
    int t = threadIdx.x;
    int i = blockIdx.x * 1024 + t;
    s[t] = (i < n) ? cnt[i] : 0;
    __syncthreads();
    for (int st = 512; st > 0; st >>= 1) {
        if (t < st) s[t] += s[t + st];
        __syncthreads();
    }
    if (t == 0) part[blockIdx.x] = s[0];
}

__global__ __launch_bounds__(1024) void part_scan_kernel(int* __restrict__ part, int nb,
                                                         int* __restrict__ off, int ntot)
{
    __shared__ int s[1024];
    int t = threadIdx.x;
    int orig = (t < nb) ? part[t] : 0;
    s[t] = orig;
    __syncthreads();
    for (int st = 1; st < 1024; st <<= 1) {
        int add = (t >= st) ? s[t - st] : 0;
        __syncthreads();
        s[t] += add;
        __syncthreads();
    }
    if (t < nb) part[t] = s[t] - orig;
    if (t == 1023) off[ntot] = s[1023];
}

__global__ __launch_bounds__(1024) void tile_scan_kernel(const int* __restrict__ cnt, int n,
                                                         const int* __restrict__ part,
                                                         int* __restrict__ off,
                                                         int* __restrict__ cur)
{
    __shared__ int s[1024];
    int t = threadIdx.x;
    int i = blockIdx.x * 1024 + t;
    int orig = (i < n) ? cnt[i] : 0;
    s[t] = orig;
    __syncthreads();
    for (int st = 1; st < 1024; st <<= 1) {
        int add = (t >= st) ? s[t - st] : 0;
        __syncthreads();
        s[t] += add;
        __syncthreads();
    }
    if (i < n) {
        int excl = s[t] - orig + part[blockIdx.x];
        off[i] = excl;
        cur[i] = excl;
    }
}

__global__ __launch_bounds__(256) void fill_kernel(const int* __restrict__ flags,
                                                   const int* __restrict__ h32,
                                                   int* __restrict__ cur,
                                                   int* __restrict__ cv, int E, int NX)
{
    int e = blockIdx.x * 256 + threadIdx.x;
    if (e >= E) return;
    int v, u; load_edge(h32, e, E, flags[0], v, u);
    int pv = atomicAdd(&cur[v], 1);
    cv[pv] = u;
    int pe = atomicAdd(&cur[NX + u], 1);
    cv[pe] = v;
}

// ---------------- fused phase: lane-parallel gather + double MFMA + epilogue ----
// out[r] = (stab[r]@Ws^T + bs) * (1 + (sum_nbr gtab[nbr])@Wg^T + deg*bg)
// Block 256 = 4 waves, 16 rows. Gather: lane (wid,q,fn) owns row fn (=lane&15),
// features [wid*32+q*8, +8) — 16 rows progress in parallel per wave.
__global__ __launch_bounds__(256) void fused_mfma_phase(
    const int* __restrict__ flags,
    const void* __restrict__ gtab, size_t goff,
    const void* __restrict__ stab,
    const u16* __restrict__ Wg, const u16* __restrict__ Ws,
    const float* __restrict__ bg, const float* __restrict__ bs,
    const int* __restrict__ off, const int* __restrict__ cv,
    void* __restrict__ out, size_t ooff, int M)
{
    const bool F32 = (flags[1] != 0);
    const int lane = threadIdx.x & 63;
    const int wid  = threadIdx.x >> 6;
    const int fn   = lane & 15;
    const int q    = lane >> 4;
    const int feat = wid * 32 + q * 8;     // first of this lane's 8 features
    const int r0   = blockIdx.x * 16;

    __shared__ u16  sA[16][136];   // gathered-sum rows, bf16 (pad keeps b128 2-way clean)
    __shared__ u16  sS[16][136];   // self rows
    __shared__ float sdeg[16];

    float a0=0.f,a1=0.f,a2=0.f,a3=0.f,a4=0.f,a5=0.f,a6=0.f,a7=0.f;
    float s0=0.f,s1=0.f,s2=0.f,s3=0.f,s4=0.f,s5=0.f,s6=0.f,s7=0.f;
    int deg = 0;

    const int r = r0 + fn;
    if (r < M) {
        int start = off[r], end = off[r + 1];
        deg = end - start;
        if (F32) {
            const float* gt = (const float*)gtab + goff;
            int e = start;
            for (; e + 1 < end; e += 2) {
                int i0 = cv[e], i1 = cv[e + 1];
                float4 va = *(const float4*)(gt + (size_t)i0 * DD + feat);
                float4 vb = *(const float4*)(gt + (size_t)i0 * DD + feat + 4);
                float4 vc = *(const float4*)(gt + (size_t)i1 * DD + feat);
                float4 vd = *(const float4*)(gt + (size_t)i1 * DD + feat + 4);
                a0 += va.x + vc.x; a1 += va.y + vc.y; a2 += va.z + vc.z; a3 += va.w + vc.w;
                a4 += vb.x + vd.x; a5 += vb.y + vd.y; a6 += vb.z + vd.z; a7 += vb.w + vd.w;
            }
            if (e < end) {
                int i0 = cv[e];
                float4 va = *(const float4*)(gt + (size_t)i0 * DD + feat);
                float4 vb = *(const float4*)(gt + (size_t)i0 * DD + feat + 4);
                a0 += va.x; a1 += va.y; a2 += va.z; a3 += va.w;
                a4 += vb.x; a5 += vb.y; a6 += vb.z; a7 += vb.w;
            }
            const float* sp = (const float*)stab + (size_t)r * DD + feat;
            float4 sa = *(const float4*)sp;
            float4 sb = *(const float4*)(sp + 4);
            s0=sa.x; s1=sa.y; s2=sa.z; s3=sa.w; s4=sb.x; s5=sb.y; s6=sb.z; s7=sb.w;
        } else {
            const u16* gt = (const u16*)gtab + goff;
            int e = start;
            for (; e + 1 < end; e += 2) {
                int i0 = cv[e], i1 = cv[e + 1];
                uint4 pa = *(const uint4*)(gt + (size_t)i0 * DD + feat);
                uint4 pb = *(const uint4*)(gt + (size_t)i1 * DD + feat);
                a0 += blo(pa.x) + blo(pb.x); a1 += bhi(pa.x) + bhi(pb.x);
                a2 += blo(pa.y) + blo(pb.y); a3 += bhi(pa.y) + bhi(pb.y);
                a4 += blo(pa.z) + blo(pb.z); a5 += bhi(pa.z) + bhi(pb.z);
                a6 += blo(pa.w) + blo(pb.w); a7 += bhi(pa.w) + bhi(pb.w);
            }
            if (e < end) {
                uint4 pa = *(const uint4*)(gt + (size_t)cv[e] * DD + feat);
                a0 += blo(pa.x); a1 += bhi(pa.x); a2 += blo(pa.y); a3 += bhi(pa.y);
                a4 += blo(pa.z); a5 += bhi(pa.z); a6 += blo(pa.w); a7 += bhi(pa.w);
            }
            uint4 sp = *(const uint4*)((const u16*)stab + (size_t)r * DD + feat);
            s0=blo(sp.x); s1=bhi(sp.x); s2=blo(sp.y); s3=bhi(sp.y);
            s4=blo(sp.z); s5=bhi(sp.z); s6=blo(sp.w); s7=bhi(sp.w);
        }
    }

    // pack to bf16 and store this lane's A-frag slice + self slice
    uint4 pk;
    pk.x = ((u32)f2b(a1) << 16) | (u32)f2b(a0);
    pk.y = ((u32)f2b(a3) << 16) | (u32)f2b(a2);
    pk.z = ((u32)f2b(a5) << 16) | (u32)f2b(a4);
    pk.w = ((u32)f2b(a7) << 16) | (u32)f2b(a6);
    *(uint4*)&sA[fn][feat] = pk;
    pk.x = ((u32)f2b(s1) << 16) | (u32)f2b(s0);
    pk.y = ((u32)f2b(s3) << 16) | (u32)f2b(s2);
    pk.z = ((u32)f2b(s5) << 16) | (u32)f2b(s4);
    pk.w = ((u32)f2b(s7) << 16) | (u32)f2b(s6);
    *(uint4*)&sS[fn][feat] = pk;
    if (threadIdx.x < 16) sdeg[threadIdx.x] = 0.f;
    if (wid == 0 && q == 0) sdeg[fn] = (float)deg;
    __syncthreads();

    // ---- MFMA stage: wave wid covers cols [32*wid, 32*wid+32) ----
    const int qk = q * 8;

    bf16x8 Bg[2][4], Bs[2][4];
#pragma unroll
    for (int t = 0; t < 2; ++t) {
        int n = 32 * wid + 16 * t + fn;
#pragma unroll
        for (int c = 0; c < 4; ++c) {
            Bg[t][c] = *(const bf16x8*)(Wg + (size_t)n * DD + 32 * c + qk);
            Bs[t][c] = *(const bf16x8*)(Ws + (size_t)n * DD + 32 * c + qk);
        }
    }

    f32x4 accA[2], accS[2];
#pragma unroll
    for (int t = 0; t < 2; ++t)
#pragma unroll
        for (int i = 0; i < 4; ++i) { accA[t][i] = 0.f; accS[t][i] = 0.f; }

#pragma unroll
    for (int c = 0; c < 4; ++c) {
        bf16x8 Ag = *(const bf16x8*)&sA[fn][32 * c + qk];
        bf16x8 As = *(const bf16x8*)&sS[fn][32 * c + qk];
#pragma unroll
        for (int t = 0; t < 2; ++t) {
            accA[t] = __builtin_amdgcn_mfma_f32_16x16x32_bf16(Ag, Bg[t][c], accA[t], 0, 0, 0);
            accS[t] = __builtin_amdgcn_mfma_f32_16x16x32_bf16(As, Bs[t][c], accS[t], 0, 0, 0);
        }
    }

    // ---- epilogue: D row=(lane>>4)*4+i, col=lane&15 (+tile base) ----
#pragma unroll
    for (int t = 0; t < 2; ++t) {
        int col = 32 * wid + 16 * t + fn;
        float bsv = bs[col], bgv = bg[col];
#pragma unroll
        for (int i = 0; i < 4; ++i) {
            int rr = q * 4 + i;
            int rw = r0 + rr;
            if (rw >= M) continue;
            float S = accS[t][i] + bsv;
            float A = accA[t][i] + sdeg[rr] * bgv;
            float res = S * (1.f + A);
            if (F32) ((float*)out)[ooff + (size_t)rw * DD + col] = res;
            else     ((u16*)out)[ooff + (size_t)rw * DD + col] = f2b(res);
        }
    }
}

static inline size_t alignup(size_t v){ return (v + 255) & ~(size_t)255; }

extern "C" void kernel_launch(void* const* d_in, const int* in_sizes, int n_in,
                              void* d_out, int out_size, void* d_ws, size_t ws_size,
                              hipStream_t stream)
{
    const int NX = in_sizes[0] / DD;    // 100000
    const int NW = in_sizes[1] / DD;    // 25000
    const int E  = in_sizes[10] / 2;    // 800000
    const int NT = NX + NW;

    const void* x   = d_in[0];
    const void* w   = d_in[1];
    const int*  h32 = (const int*)d_in[10];

    // workspace (~7.7 MB)
    char* ws = (char*)d_ws;
    size_t o = 0;
    int*   flags   = (int*)(ws + o); o = alignup(o + sizeof(int) * 8);
    int*   off_all = (int*)(ws + o); o = alignup(o + sizeof(int) * (size_t)(NT + 1));
    int*   cur_all = (int*)(ws + o); o = alignup(o + sizeof(int) * (size_t)NT);
    int*   part    = (int*)(ws + o); o = alignup(o + sizeof(int) * 1024);
    u16*   Wb      = (u16*)(ws + o); o = alignup(o + sizeof(u16) * 65536);
    float* canonB  = (float*)(ws + o); o = alignup(o + sizeof(float) * 512);
    int*   cv_all  = (int*)(ws + o); o = alignup(o + sizeof(int) * (size_t)2 * E);

    detect_kernel<<<1, 256, 0, stream>>>(h32, E, (const u32*)x, flags);

    canon_kernel<<<(66048 + 255) / 256, 256, 0, stream>>>(
        flags, d_in[4], d_in[2], d_in[6], d_in[8],   // Ww1, Wx1, Wx2, Ww2
               d_in[5], d_in[3], d_in[7], d_in[9],   // bw1, bx1, bx2, bw2
        Wb, canonB);

    hipMemsetAsync(cur_all, 0, sizeof(int) * (size_t)NT, stream);

    int eb = (E + 255) / 256;
    int nb = (NT + 1023) / 1024;
    hist_kernel<<<eb, 256, 0, stream>>>(flags, h32, cur_all, E, NX);
    tile_sum_kernel<<<nb, 1024, 0, stream>>>(cur_all, NT, part);
    part_scan_kernel<<<1, 1024, 0, stream>>>(part, nb, off_all, NT);
    tile_scan_kernel<<<nb, 1024, 0, stream>>>(cur_all, NT, part, off_all, cur_all);
    fill_kernel<<<eb, 256, 0, stream>>>(flags, h32, cur_all, cv_all, E, NX);

    // out layout: [w_new (NW*DD) | x_new (NX*DD)] in detected dtype
    size_t xoff = (size_t)NW * DD;

    // Phase 1 (MPToVertex): x_new = (x@Wx1^T+bx1) * (1 + segsum_v(w)@Ww1^T + deg_v*bw1)
    fused_mfma_phase<<<(NX + 15) / 16, 256, 0, stream>>>(
        flags, w, 0, x,
        Wb + 0 * 16384, Wb + 1 * 16384, canonB + 0, canonB + 128,
        off_all, cv_all, d_out, xoff, NX);

    // Phase 2 (MPToEdge): w_new = (w@Ww2^T+bw2) * (1 + segsum_e(x_new)@Wx2^T + deg_e*bx2)
    fused_mfma_phase<<<(NW + 15) / 16, 256, 0, stream>>>(
        flags, d_out, xoff, w,
        Wb + 2 * 16384, Wb + 3 * 16384, canonB + 256, canonB + 384,
        off_all + NX, cv_all, d_out, 0, NW);
}

// Round 6
// 395.182 us; speedup vs baseline: 3.9562x; 1.3584x over previous
//
#include <hip/hip_runtime.h>

#define DD 128
#define SH 7            // bucket = key >> SH ; keys per bucket = 128

typedef unsigned short u16;
typedef unsigned int   u32;
typedef __attribute__((ext_vector_type(8))) short bf16x8;
typedef __attribute__((ext_vector_type(4))) float f32x4;

__device__ __forceinline__ float blo(u32 u){ return __uint_as_float(u << 16); }
__device__ __forceinline__ float bhi(u32 u){ return __uint_as_float(u & 0xFFFF0000u); }
__device__ __forceinline__ u16 f2b(float f){
    u32 u = __float_as_uint(f);
    u32 r = u + 0x7FFFu + ((u >> 16) & 1u);
    return (u16)(r >> 16);
}

// ---------------- runtime environment detection ----------------
// flags[0] = 1 if h is int64 ; flags[1] = 1 if float inputs are f32
__global__ __launch_bounds__(256) void detect_kernel(const int* __restrict__ h32, int E,
                                                     const u32* __restrict__ xw,
                                                     int* __restrict__ flags)
{
    __shared__ int nzodd, sane;
    if (threadIdx.x == 0) { nzodd = 0; sane = 0; }
    __syncthreads();
    if (threadIdx.x < 64 && h32[2 * threadIdx.x + 1] != 0) atomicAdd(&nzodd, 1);
    for (int i = (int)threadIdx.x; i < 1024; i += 256) {
        u32 lo = xw[i] & 0xFFFFu;
        u32 ex = (lo >> 7) & 0xFFu;
        if (ex >= 100u && ex <= 140u) atomicAdd(&sane, 1);
    }
    __syncthreads();
    if (threadIdx.x == 0) {
        flags[0] = (nzodd == 0) ? 1 : 0;
        flags[1] = (sane < 700) ? 1 : 0;
    }
}

// ---------------- canonicalize weights (bf16) + biases (f32) ----------------
__global__ __launch_bounds__(256) void canon_kernel(
    const int* __restrict__ flags,
    const void* W0, const void* W1, const void* W2, const void* W3,
    const void* B0, const void* B1, const void* B2, const void* B3,
    u16* __restrict__ Wb, float* __restrict__ canonB)
{
    int idx = blockIdx.x * 256 + threadIdx.x;
    bool f32 = (flags[1] != 0);
    if (idx < 65536) {
        int m = idx >> 14, o = idx & 16383;
        const void* src;
        switch (m) { case 0: src = W0; break; case 1: src = W1; break;
                     case 2: src = W2; break; default: src = W3; }
        float v = f32 ? ((const float*)src)[o] : blo(((const u16*)src)[o]);
        Wb[idx] = f2b(v);
    } else {
        int j = idx - 65536; if (j >= 512) return;
        int m = j >> 7, o = j & 127;
        const void* src;
        switch (m) { case 0: src = B0; break; case 1: src = B1; break;
                     case 2: src = B2; break; default: src = B3; }
        canonB[j] = f32 ? ((const float*)src)[o] : blo(((const u16*)src)[o]);
    }
}

// ---------------- bucketed CSR build ----------------
__device__ __forceinline__ void load_edge(const int* __restrict__ h32, int e, int E,
                                          int idx64, int& v, int& u)
{
    if (idx64) { v = h32[2 * e]; u = h32[2 * E + 2 * e]; }
    else       { v = h32[e];     u = h32[E + e]; }
}

// K1: global bucket histogram (LDS-staged)
__global__ __launch_bounds__(256) void bucket_hist(const int* __restrict__ flags,
                                                   const int* __restrict__ h32,
                                                   int* __restrict__ bcnt,
                                                   int E, int NX, int NB)
{
    __shared__ int hist[1024];
    int tid = threadIdx.x;
    for (int i = tid; i < 1024; i += 256) hist[i] = 0;
    __syncthreads();
    int base = blockIdx.x * 4096;
    int idx64 = flags[0];
    for (int k = 0; k < 16; ++k) {
        int e = base + k * 256 + tid;
        if (e < E) {
            int v, u; load_edge(h32, e, E, idx64, v, u);
            atomicAdd(&hist[v >> SH], 1);
            atomicAdd(&hist[(NX + u) >> SH], 1);
        }
    }
    __syncthreads();
    for (int i = tid; i < NB; i += 256)
        if (hist[i]) atomicAdd(&bcnt[i], hist[i]);
}

// K2: scan bucket counts (NB <= 1024), init cursors, write off_all[NT]
__global__ __launch_bounds__(1024) void bucket_scan(const int* __restrict__ bcnt, int NB,
                                                    int* __restrict__ boff,
                                                    int* __restrict__ bcur,
                                                    int* __restrict__ off_all,
                                                    int NT, int total)
{
    __shared__ int s[1024];
    int t = threadIdx.x;
    int v = (t < NB) ? bcnt[t] : 0;
    s[t] = v;
    __syncthreads();
    for (int st = 1; st < 1024; st <<= 1) {
        int a = (t >= st) ? s[t - st] : 0;
        __syncthreads();
        s[t] += a;
        __syncthreads();
    }
    if (t < NB) { int excl = s[t] - v; boff[t] = excl; bcur[t] = excl; }
    if (t == 0) { boff[NB] = total; off_all[NT] = total; }
}

// K3: per-block counting sort into bucket-major record array (rec = (nbr<<7)|key_low7)
__global__ __launch_bounds__(256) void bucket_fill(const int* __restrict__ flags,
                                                   const int* __restrict__ h32,
                                                   int E, int NX, int NB,
                                                   int* __restrict__ bcur,
                                                   u32* __restrict__ recs)
{
    __shared__ u32 staged[8192];
    __shared__ int hist[1024], lstart[1024], gbase[1024], cur[1024];
    __shared__ int tscan[256];
    const int tid = threadIdx.x;
    const int base = blockIdx.x * 4096;
    const int idx64 = flags[0];

    for (int i = tid; i < 1024; i += 256) hist[i] = 0;
    __syncthreads();
    // pass 1: histogram
    for (int k = 0; k < 16; ++k) {
        int e = base + k * 256 + tid;
        if (e < E) {
            int v, u; load_edge(h32, e, E, idx64, v, u);
            atomicAdd(&hist[v >> SH], 1);
            atomicAdd(&hist[(NX + u) >> SH], 1);
        }
    }
    __syncthreads();
    // exclusive scan of hist -> lstart (4 buckets per thread + block scan)
    int b0 = tid * 4;
    int c0 = hist[b0], c1 = hist[b0 + 1], c2 = hist[b0 + 2], c3 = hist[b0 + 3];
    int sum = c0 + c1 + c2 + c3;
    tscan[tid] = sum;
    __syncthreads();
    for (int st = 1; st < 256; st <<= 1) {
        int a = (tid >= st) ? tscan[tid - st] : 0;
        __syncthreads();
        tscan[tid] += a;
        __syncthreads();
    }
    int run = tscan[tid] - sum;
    lstart[b0] = run; run += c0;
    lstart[b0 + 1] = run; run += c1;
    lstart[b0 + 2] = run; run += c2;
    lstart[b0 + 3] = run;
    __syncthreads();
    for (int i = tid; i < 1024; i += 256) cur[i] = lstart[i];
    __syncthreads();
    // pass 2: scatter records into staged (bucket-major within block)
    for (int k = 0; k < 16; ++k) {
        int e = base + k * 256 + tid;
        if (e < E) {
            int v, u; load_edge(h32, e, E, idx64, v, u);
            u32 r1 = ((u32)u << 7) | (u32)(v & 127);
            int p1 = atomicAdd(&cur[v >> SH], 1);
            staged[p1] = r1;
            int key2 = NX + u;
            u32 r2 = ((u32)v << 7) | (u32)(key2 & 127);
            int p2 = atomicAdd(&cur[key2 >> SH], 1);
            staged[p2] = r2;
        }
    }
    __syncthreads();
    // allocate global runs
    for (int i = tid; i < NB; i += 256) {
        int c = hist[i];
        gbase[i] = c ? atomicAdd(&bcur[i], c) : 0;
    }
    __syncthreads();
    // cooperative coalesced flush (binary search bucket per record)
    int nrec = tscan[255];
    for (int i = tid; i < nrec; i += 256) {
        u32 r = staged[i];
        int lo = 0, hi = NB - 1;
        while (lo < hi) {
            int mid = (lo + hi + 1) >> 1;
            if (lstart[mid] <= i) lo = mid; else hi = mid - 1;
        }
        recs[gbase[lo] + (i - lstart[lo])] = r;
    }
}

// K4: one block per bucket — local 128-key sort IN PLACE, emit off_all + cv
__global__ __launch_bounds__(256) void bucket_to_csr(const int* __restrict__ boff,
                                                     int NB, int NT,
                                                     u32* __restrict__ recs,
                                                     int* __restrict__ off_all)
{
    __shared__ u32 buf[8192];
    __shared__ int hist[128], lofs[128], cur[128];
    const int b = blockIdx.x;
    const int tid = threadIdx.x;
    const int s = boff[b];
    const int n = boff[b + 1] - s;

    if (tid < 128) hist[tid] = 0;
    __syncthreads();
    for (int i = tid; i < n; i += 256) {
        u32 r = recs[s + i];
        buf[i] = r;
        atomicAdd(&hist[r & 127], 1);
    }
    __syncthreads();
    if (tid < 128) lofs[tid] = hist[tid];
    __syncthreads();
    for (int st = 1; st < 128; st <<= 1) {
        int a = 0;
        if (tid < 128 && tid >= st) a = lofs[tid - st];
        __syncthreads();
        if (tid < 128) lofs[tid] += a;
        __syncthreads();
    }
    if (tid < 128) {
        int excl = lofs[tid] - hist[tid];
        int key = (b << SH) + tid;
        if (key < NT) off_all[key] = s + excl;
        cur[tid] = excl;
    }
    __syncthreads();
    for (int i = tid; i < n; i += 256) {
        u32 r = buf[i];
        int p = atomicAdd(&cur[r & 127], 1);
        recs[s + p] = r >> 7;      // final cv value = neighbor id
    }
}

// ---------------- fused phase: lane-parallel gather + double MFMA + epilogue ----
__global__ __launch_bounds__(256) void fused_mfma_phase(
    const int* __restrict__ flags,
    const void* __restrict__ gtab, size_t goff,
    const void* __restrict__ stab,
    const u16* __restrict__ Wg, const u16* __restrict__ Ws,
    const float* __restrict__ bg, const float* __restrict__ bs,
    const int* __restrict__ off, const int* __restrict__ cv,
    void* __restrict__ out, size_t ooff, int M)
{
    const bool F32 = (flags[1] != 0);
    const int lane = threadIdx.x & 63;
    const int wid  = threadIdx.x >> 6;
    const int fn   = lane & 15;
    const int q    = lane >> 4;
    const int feat = wid * 32 + q * 8;
    const int r0   = blockIdx.x * 16;

    __shared__ u16  sA[16][136];
    __shared__ u16  sS[16][136];
    __shared__ float sdeg[16];

    float a0=0.f,a1=0.f,a2=0.f,a3=0.f,a4=0.f,a5=0.f,a6=0.f,a7=0.f;
    float s0=0.f,s1=0.f,s2=0.f,s3=0.f,s4=0.f,s5=0.f,s6=0.f,s7=0.f;
    int deg = 0;

    const int r = r0 + fn;
    if (r < M) {
        int start = off[r], end = off[r + 1];
        deg = end - start;
        if (F32) {
            const float* gt = (const float*)gtab + goff;
            int e = start;
            for (; e + 1 < end; e += 2) {
                int i0 = cv[e], i1 = cv[e + 1];
                float4 va = *(const float4*)(gt + (size_t)i0 * DD + feat);
                float4 vb = *(const float4*)(gt + (size_t)i0 * DD + feat + 4);
                float4 vc = *(const float4*)(gt + (size_t)i1 * DD + feat);
                float4 vd = *(const float4*)(gt + (size_t)i1 * DD + feat + 4);
                a0 += va.x + vc.x; a1 += va.y + vc.y; a2 += va.z + vc.z; a3 += va.w + vc.w;
                a4 += vb.x + vd.x; a5 += vb.y + vd.y; a6 += vb.z + vd.z; a7 += vb.w + vd.w;
            }
            if (e < end) {
                int i0 = cv[e];
                float4 va = *(const float4*)(gt + (size_t)i0 * DD + feat);
                float4 vb = *(const float4*)(gt + (size_t)i0 * DD + feat + 4);
                a0 += va.x; a1 += va.y; a2 += va.z; a3 += va.w;
                a4 += vb.x; a5 += vb.y; a6 += vb.z; a7 += vb.w;
            }
            const float* sp = (const float*)stab + (size_t)r * DD + feat;
            float4 sa = *(const float4*)sp;
            float4 sb = *(const float4*)(sp + 4);
            s0=sa.x; s1=sa.y; s2=sa.z; s3=sa.w; s4=sb.x; s5=sb.y; s6=sb.z; s7=sb.w;
        } else {
            const u16* gt = (const u16*)gtab + goff;
            int e = start;
            for (; e + 1 < end; e += 2) {
                int i0 = cv[e], i1 = cv[e + 1];
                uint4 pa = *(const uint4*)(gt + (size_t)i0 * DD + feat);
                uint4 pb = *(const uint4*)(gt + (size_t)i1 * DD + feat);
                a0 += blo(pa.x) + blo(pb.x); a1 += bhi(pa.x) + bhi(pb.x);
                a2 += blo(pa.y) + blo(pb.y); a3 += bhi(pa.y) + bhi(pb.y);
                a4 += blo(pa.z) + blo(pb.z); a5 += bhi(pa.z) + bhi(pb.z);
                a6 += blo(pa.w) + blo(pb.w); a7 += bhi(pa.w) + bhi(pb.w);
            }
            if (e < end) {
                uint4 pa = *(const uint4*)(gt + (size_t)cv[e] * DD + feat);
                a0 += blo(pa.x); a1 += bhi(pa.x); a2 += blo(pa.y); a3 += bhi(pa.y);
                a4 += blo(pa.z); a5 += bhi(pa.z); a6 += blo(pa.w); a7 += bhi(pa.w);
            }
            uint4 sp = *(const uint4*)((const u16*)stab + (size_t)r * DD + feat);
            s0=blo(sp.x); s1=bhi(sp.x); s2=blo(sp.y); s3=bhi(sp.y);
            s4=blo(sp.z); s5=bhi(sp.z); s6=blo(sp.w); s7=bhi(sp.w);
        }
    }

    uint4 pk;
    pk.x = ((u32)f2b(a1) << 16) | (u32)f2b(a0);
    pk.y = ((u32)f2b(a3) << 16) | (u32)f2b(a2);
    pk.z = ((u32)f2b(a5) << 16) | (u32)f2b(a4);
    pk.w = ((u32)f2b(a7) << 16) | (u32)f2b(a6);
    *(uint4*)&sA[fn][feat] = pk;
    pk.x = ((u32)f2b(s1) << 16) | (u32)f2b(s0);
    pk.y = ((u32)f2b(s3) << 16) | (u32)f2b(s2);
    pk.z = ((u32)f2b(s5) << 16) | (u32)f2b(s4);
    pk.w = ((u32)f2b(s7) << 16) | (u32)f2b(s6);
    *(uint4*)&sS[fn][feat] = pk;
    if (threadIdx.x < 16) sdeg[threadIdx.x] = 0.f;
    if (wid == 0 && q == 0) sdeg[fn] = (float)deg;
    __syncthreads();

    const int qk = q * 8;
    bf16x8 Bg[2][4], Bs[2][4];
#pragma unroll
    for (int t = 0; t < 2; ++t) {
        int n = 32 * wid + 16 * t + fn;
#pragma unroll
        for (int c = 0; c < 4; ++c) {
            Bg[t][c] = *(const bf16x8*)(Wg + (size_t)n * DD + 32 * c + qk);
            Bs[t][c] = *(const bf16x8*)(Ws + (size_t)n * DD + 32 * c + qk);
        }
    }

    f32x4 accA[2], accS[2];
#pragma unroll
    for (int t = 0; t < 2; ++t)
#pragma unroll
        for (int i = 0; i < 4; ++i) { accA[t][i] = 0.f; accS[t][i] = 0.f; }

#pragma unroll
    for (int c = 0; c < 4; ++c) {
        bf16x8 Ag = *(const bf16x8*)&sA[fn][32 * c + qk];
        bf16x8 As = *(const bf16x8*)&sS[fn][32 * c + qk];
#pragma unroll
        for (int t = 0; t < 2; ++t) {
            accA[t] = __builtin_amdgcn_mfma_f32_16x16x32_bf16(Ag, Bg[t][c], accA[t], 0, 0, 0);
            accS[t] = __builtin_amdgcn_mfma_f32_16x16x32_bf16(As, Bs[t][c], accS[t], 0, 0, 0);
        }
    }

#pragma unroll
    for (int t = 0; t < 2; ++t) {
        int col = 32 * wid + 16 * t + fn;
        float bsv = bs[col], bgv = bg[col];
#pragma unroll
        for (int i = 0; i < 4; ++i) {
            int rr = q * 4 + i;
            int rw = r0 + rr;
            if (rw >= M) continue;
            float S = accS[t][i] + bsv;
            float A = accA[t][i] + sdeg[rr] * bgv;
            float res = S * (1.f + A);
            if (F32) ((float*)out)[ooff + (size_t)rw * DD + col] = res;
            else     ((u16*)out)[ooff + (size_t)rw * DD + col] = f2b(res);
        }
    }
}

static inline size_t alignup(size_t v){ return (v + 255) & ~(size_t)255; }

extern "C" void kernel_launch(void* const* d_in, const int* in_sizes, int n_in,
                              void* d_out, int out_size, void* d_ws, size_t ws_size,
                              hipStream_t stream)
{
    const int NX = in_sizes[0] / DD;    // 100000
    const int NW = in_sizes[1] / DD;    // 25000
    const int E  = in_sizes[10] / 2;    // 800000
    const int NT = NX + NW;
    const int NB = (NT + ((1 << SH) - 1)) >> SH;   // 977 (<= 1024 required)

    const void* x   = d_in[0];
    const void* w   = d_in[1];
    const int*  h32 = (const int*)d_in[10];

    // workspace (~7.05 MB)
    char* ws = (char*)d_ws;
    size_t o = 0;
    int*   flags   = (int*)(ws + o); o = alignup(o + sizeof(int) * 8);
    int*   off_all = (int*)(ws + o); o = alignup(o + sizeof(int) * (size_t)(NT + 1));
    int*   boff    = (int*)(ws + o); o = alignup(o + sizeof(int) * (size_t)(NB + 1));
    int*   bcnt    = (int*)(ws + o); o = alignup(o + sizeof(int) * (size_t)NB);
    int*   bcur    = (int*)(ws + o); o = alignup(o + sizeof(int) * (size_t)NB);
    u16*   Wb      = (u16*)(ws + o); o = alignup(o + sizeof(u16) * 65536);
    float* canonB  = (float*)(ws + o); o = alignup(o + sizeof(float) * 512);
    u32*   cv_all  = (u32*)(ws + o); o = alignup(o + sizeof(u32) * (size_t)2 * E);

    detect_kernel<<<1, 256, 0, stream>>>(h32, E, (const u32*)x, flags);

    canon_kernel<<<(66048 + 255) / 256, 256, 0, stream>>>(
        flags, d_in[4], d_in[2], d_in[6], d_in[8],   // Ww1, Wx1, Wx2, Ww2
               d_in[5], d_in[3], d_in[7], d_in[9],   // bw1, bx1, bx2, bw2
        Wb, canonB);

    hipMemsetAsync(bcnt, 0, sizeof(int) * (size_t)NB, stream);

    int eb4k = (E + 4095) / 4096;
    bucket_hist<<<eb4k, 256, 0, stream>>>(flags, h32, bcnt, E, NX, NB);
    bucket_scan<<<1, 1024, 0, stream>>>(bcnt, NB, boff, bcur, off_all, NT, 2 * E);
    bucket_fill<<<eb4k, 256, 0, stream>>>(flags, h32, E, NX, NB, bcur, cv_all);
    bucket_to_csr<<<NB, 256, 0, stream>>>(boff, NB, NT, cv_all, off_all);

    // out layout: [w_new (NW*DD) | x_new (NX*DD)] in detected dtype
    size_t xoff = (size_t)NW * DD;

    // Phase 1 (MPToVertex): x_new = (x@Wx1^T+bx1) * (1 + segsum_v(w)@Ww1^T + deg_v*bw1)
    fused_mfma_phase<<<(NX + 15) / 16, 256, 0, stream>>>(
        flags, w, 0, x,
        Wb + 0 * 16384, Wb + 1 * 16384, canonB + 0, canonB + 128,
        off_all, (const int*)cv_all, d_out, xoff, NX);

    // Phase 2 (MPToEdge): w_new = (w@Ww2^T+bw2) * (1 + segsum_e(x_new)@Wx2^T + deg_e*bx2)
    fused_mfma_phase<<<(NW + 15) / 16, 256, 0, stream>>>(
        flags, d_out, xoff, w,
        Wb + 2 * 16384, Wb + 3 * 16384, canonB + 256, canonB + 384,
        off_all + NX, (const int*)cv_all, d_out, 0, NW);
}